// Round 3
// baseline (736.886 us; speedup 1.0000x reference)
//
#include <hip/hip_runtime.h>
#include <math.h>

#define BB 32
#define LL 2048
#define HH 2048

// ---------------------------------------------------------------------------
// Kernel 1: split-K partials of u = hidden @ W   (u[b,h] = sum_g hid[b,g]*W[g,h])
// grid (HH/256, gchunks), block 256. Thread owns one column h, a g-range,
// and all 32 batches in registers. W read is fully coalesced; hidden reads
// are wave-uniform -> scalar loads.
// ---------------------------------------------------------------------------
__global__ __launch_bounds__(256) void k_proj_partial(
    const float* __restrict__ hid, const float* __restrict__ W,
    float* __restrict__ part, int gspan) {
  const int h = blockIdx.x * 256 + threadIdx.x;
  const int g0 = blockIdx.y * gspan;
  float acc[BB];
#pragma unroll
  for (int b = 0; b < BB; ++b) acc[b] = 0.f;
#pragma unroll 4
  for (int gi = 0; gi < gspan; ++gi) {
    const int g = g0 + gi;
    const float w = W[(size_t)g * HH + h];
#pragma unroll
    for (int b = 0; b < BB; ++b) acc[b] = fmaf(hid[b * HH + g], w, acc[b]);
  }
  float* dst = part + ((size_t)blockIdx.y * BB) * HH + h;
#pragma unroll
  for (int b = 0; b < BB; ++b) dst[(size_t)b * HH] = acc[b];
}

// Reduce the gchunks partials into u[b,h]. Deterministic (no atomics).
__global__ __launch_bounds__(256) void k_proj_reduce(
    const float* __restrict__ part, float* __restrict__ u, int gchunks) {
  const int i = blockIdx.x * 256 + threadIdx.x;  // index over B*H
  float s = 0.f;
  for (int c = 0; c < gchunks; ++c) s += part[(size_t)c * BB * HH + i];
  u[i] = s;
}

// ---------------------------------------------------------------------------
// Kernel 2: energies[b,l] = dot(enc[b,l,:], u[b,:])  -- THE memory-bound pass.
// grid (LL/64, BB), block 256 (4 waves). u[b] staged in LDS (8 KiB). Each wave
// computes one row at a time: 8 x global_load_dwordx4 (coalesced, 1 KiB/instr)
// + fma, then a 6-step shuffle reduce. Writes energies into d_out[b*L+l].
// ---------------------------------------------------------------------------
__global__ __launch_bounds__(256) void k_energy(
    const float* __restrict__ enc, const float* __restrict__ u,
    float* __restrict__ energies) {
  __shared__ float vs[HH];
  const int b = blockIdx.y;
  const int t = threadIdx.x;

  const float4* vsrc = reinterpret_cast<const float4*>(u + (size_t)b * HH);
  float4* vdst = reinterpret_cast<float4*>(vs);
  vdst[t] = vsrc[t];
  vdst[t + 256] = vsrc[t + 256];
  __syncthreads();

  const int wave = t >> 6;
  const int lane = t & 63;
  const float4* vls = reinterpret_cast<const float4*>(vs);

#pragma unroll 1
  for (int it = 0; it < 16; ++it) {
    const int l = blockIdx.x * 64 + it * 4 + wave;
    const float4* row = reinterpret_cast<const float4*>(enc + ((size_t)b * LL + l) * HH);
    float acc = 0.f;
#pragma unroll
    for (int k = 0; k < 8; ++k) {
      const float4 e = row[k * 64 + lane];
      const float4 w = vls[k * 64 + lane];
      acc = fmaf(e.x, w.x, acc);
      acc = fmaf(e.y, w.y, acc);
      acc = fmaf(e.z, w.z, acc);
      acc = fmaf(e.w, w.w, acc);
    }
#pragma unroll
    for (int off = 32; off >= 1; off >>= 1) acc += __shfl_xor(acc, off, 64);
    if (lane == 0) energies[(size_t)b * LL + l] = acc;
  }
}

// ---------------------------------------------------------------------------
// Kernel 3: in-place row softmax over L=2048, one block per batch.
// NOTE: the bias term c[b] = dot(b, hidden[b]) is a per-row constant and
// softmax is shift-invariant, so it is dropped exactly (b is zeros anyway).
// ---------------------------------------------------------------------------
__global__ __launch_bounds__(256) void k_softmax(float* __restrict__ e) {
  const int b = blockIdx.x;
  const int t = threadIdx.x;
  float* row = e + (size_t)b * LL;

  float x[8];
  float m = -3.0e38f;
#pragma unroll
  for (int j = 0; j < 8; ++j) {
    x[j] = row[t + j * 256];
    m = fmaxf(m, x[j]);
  }
#pragma unroll
  for (int off = 32; off >= 1; off >>= 1) m = fmaxf(m, __shfl_xor(m, off, 64));

  __shared__ float sm[4];
  __shared__ float ss[4];
  const int wave = t >> 6;
  const int lane = t & 63;
  if (lane == 0) sm[wave] = m;
  __syncthreads();
  m = fmaxf(fmaxf(sm[0], sm[1]), fmaxf(sm[2], sm[3]));

  float s = 0.f;
#pragma unroll
  for (int j = 0; j < 8; ++j) {
    x[j] = expf(x[j] - m);
    s += x[j];
  }
#pragma unroll
  for (int off = 32; off >= 1; off >>= 1) s += __shfl_xor(s, off, 64);
  if (lane == 0) ss[wave] = s;
  __syncthreads();
  s = ss[0] + ss[1] + ss[2] + ss[3];

  const float inv = 1.f / s;
#pragma unroll
  for (int j = 0; j < 8; ++j) row[t + j * 256] = x[j] * inv;
}

extern "C" void kernel_launch(void* const* d_in, const int* in_sizes, int n_in,
                              void* d_out, int out_size, void* d_ws, size_t ws_size,
                              hipStream_t stream) {
  const float* hid = (const float*)d_in[0];  // [B,1,H]
  const float* enc = (const float*)d_in[1];  // [B,L,H]
  const float* W   = (const float*)d_in[2];  // [H,H]
  // d_in[3] = bias b: per-row-constant contribution, cancels in softmax.
  float* out = (float*)d_out;                // [B,L,1] flat

  // Workspace: gchunks partial u tiles + final u. Adapt gchunks to ws_size.
  int gchunks = 32;
  while (gchunks > 1 &&
         (size_t)(gchunks + 1) * BB * HH * sizeof(float) > ws_size)
    gchunks >>= 1;
  float* part = (float*)d_ws;
  float* u = part + (size_t)gchunks * BB * HH;

  dim3 g1(HH / 256, gchunks);
  k_proj_partial<<<g1, 256, 0, stream>>>(hid, W, part, HH / gchunks);
  k_proj_reduce<<<(BB * HH) / 256, 256, 0, stream>>>(part, u, gchunks);

  dim3 g2(LL / 64, BB);
  k_energy<<<g2, 256, 0, stream>>>(enc, u, out);
  k_softmax<<<BB, 256, 0, stream>>>(out);
}